// Round 4
// baseline (142.454 us; speedup 1.0000x reference)
//
#include <hip/hip_runtime.h>
#include <hip/hip_bf16.h>

// Problem constants
#define BB 4
#define NN 2048
#define DD 256
#define HH 8
#define ZZ 64
#define SPLIT 8
#define CHUNK (NN/SPLIT)   // 256

typedef __attribute__((ext_vector_type(8))) short bf16x8;
typedef __attribute__((ext_vector_type(4))) float f32x4;
typedef __attribute__((ext_vector_type(2))) float f32x2;
typedef __attribute__((ext_vector_type(4))) unsigned short us4;
typedef __attribute__((ext_vector_type(8))) unsigned short us8;

static __device__ __forceinline__ unsigned short f2bf(float f){
  unsigned int u = __float_as_uint(f);
  u = (u + 0x7fffu + ((u>>16)&1u)) >> 16;   // RNE truncate to bf16
  return (unsigned short)u;
}

// raw v_exp_f32: computes 2^x (log2e folded into the mix weights)
static __device__ __forceinline__ float fexp2(float x){
  float r; asm("v_exp_f32 %0, %1" : "=v"(r) : "v"(x)); return r;
}

// ---------------------------------------------------------------------------
// Kernel 0: convert g (f32 -> bf16) and Wq||Wk (f32 -> bf16, [1024][256]),
// and zero the output scalar (d_out is poisoned before timing).
// ---------------------------------------------------------------------------
__global__ __launch_bounds__(256) void cvt_kernel(
    const float* __restrict__ g, const float* __restrict__ Wq,
    const float* __restrict__ Wk, unsigned short* __restrict__ gb,
    unsigned short* __restrict__ wb, float* __restrict__ out)
{
  int idx = blockIdx.x*256 + threadIdx.x;
  if (idx == 0) out[0] = 0.0f;
  if (idx < 524288){
    const float4 v = ((const float4*)g)[idx];
    us4 o = { f2bf(v.x), f2bf(v.y), f2bf(v.z), f2bf(v.w) };
    *(us4*)(gb + (size_t)idx*4) = o;
  } else {
    int j = idx - 524288;                   // 0..65535
    const float4 v = (j < 32768) ? ((const float4*)Wq)[j]
                                 : ((const float4*)Wk)[j - 32768];
    us4 o = { f2bf(v.x), f2bf(v.y), f2bf(v.z), f2bf(v.w) };
    int dst = (j < 32768) ? j*4 : 131072 + (j - 32768)*4;
    *(us4*)(wb + dst) = o;
  }
}

// ---------------------------------------------------------------------------
// Kernel 1: projection GEMM (unchanged — correct). q/k stored [b][h][n][z].
// ---------------------------------------------------------------------------
__global__ __launch_bounds__(256) void proj_kernel(
    const unsigned short* __restrict__ gb, const unsigned short* __restrict__ wb,
    unsigned short* __restrict__ qb, unsigned short* __restrict__ kb)
{
  __shared__ __align__(16) unsigned short As[64][40];
  __shared__ __align__(16) unsigned short Bs[64][40];
  int tid = threadIdx.x;
  int l = tid & 63, w = tid >> 6;
  int bid = blockIdx.x;
  int rt = bid >> 4, ct = bid & 15;
  int row0 = rt*64, col0 = ct*64;

  f32x4 acc[4];
  #pragma unroll
  for (int cf=0; cf<4; ++cf) acc[cf] = 0.0f;

  int sr = tid >> 2, sc = (tid & 3)*8;
  const unsigned short* ga = gb + (size_t)(row0 + sr)*256 + sc;
  const unsigned short* gw = wb + (size_t)(col0 + sr)*256 + sc;

  for (int ks=0; ks<8; ++ks){
    us8 av = *(const us8*)(ga + ks*32);
    us8 bv = *(const us8*)(gw + ks*32);
    *(us8*)&As[sr][sc] = av;
    *(us8*)&Bs[sr][sc] = bv;
    __syncthreads();
    bf16x8 af = *(const bf16x8*)&As[w*16 + (l&15)][(l>>4)*8];
    #pragma unroll
    for (int cf=0; cf<4; ++cf){
      bf16x8 bf = *(const bf16x8*)&Bs[cf*16 + (l&15)][(l>>4)*8];
      acc[cf] = __builtin_amdgcn_mfma_f32_16x16x32_bf16(af, bf, acc[cf], 0,0,0);
    }
    __syncthreads();
  }

  int h = (col0 >> 6) & 7;
  unsigned short* outp = (col0 < 512) ? qb : kb;
  #pragma unroll
  for (int cf=0; cf<4; ++cf){
    int z = cf*16 + (l & 15);
    #pragma unroll
    for (int i=0; i<4; ++i){
      int row = row0 + w*16 + (l>>4)*4 + i;
      int b_ = row >> 11, n_ = row & 2047;
      outp[(size_t)((b_*8 + h)*2048 + n_)*64 + z] = f2bf(acc[cf][i]);
    }
  }
}

// ---------------------------------------------------------------------------
// Kernel 2: fused scores + head-mix + exp accumulation.
// 256-thread blocks, 4 independent waves (no LDS/barriers), each wave one
// 16-row n-tile; all 4 waves share one 256-wide m-chunk (L1 K reuse).
// 2-DEEP SOFTWARE PIPELINE over m-tiles: double-buffered K fragments, tile
// t+1's 16 loads issued before tile t's compute (round-3 lesson: waves get
// ~no inter-wave overlap, so each wave must self-hide L2 latency via ILP).
// log2e folded into weights so exp is a raw v_exp_f32.
// ---------------------------------------------------------------------------

#define LOADK(KV0, KV1, t) do {                                              \
  int m0_ = mstart + (t)*16;                                                 \
  _Pragma("unroll")                                                          \
  for (int h=0; h<8; ++h){                                                   \
    const unsigned short* kp = kbase + (size_t)(h*2048 + m0_)*64;            \
    KV0[h] = *(const bf16x8*)kp;                                             \
    KV1[h] = *(const bf16x8*)(kp + 32);                                      \
  }                                                                          \
} while(0)

#define COMPUTE(KV0, KV1, t) do {                                            \
  int m0_ = mstart + (t)*16;                                                 \
  f32x2 L[4][4];                                                             \
  _Pragma("unroll")                                                          \
  for (int gp=0; gp<4; ++gp)                                                 \
    _Pragma("unroll")                                                        \
    for (int i=0; i<4; ++i) L[gp][i] = 0.0f;                                 \
  _Pragma("unroll")                                                          \
  for (int h=0; h<8; ++h){                                                   \
    f32x4 tt = 0.0f;                                                         \
    tt = __builtin_amdgcn_mfma_f32_16x16x32_bf16(qf0[h], KV0[h], tt, 0,0,0); \
    tt = __builtin_amdgcn_mfma_f32_16x16x32_bf16(qf1[h], KV1[h], tt, 0,0,0); \
    _Pragma("unroll")                                                        \
    for (int i=0; i<4; ++i){                                                 \
      f32x2 ss = { tt[i], tt[i] };                                           \
      _Pragma("unroll")                                                      \
      for (int gp=0; gp<4; ++gp)                                             \
        L[gp][i] = __builtin_elementwise_fma(w2p[h][gp], ss, L[gp][i]);      \
    }                                                                        \
  }                                                                          \
  if (m0_ + 16 <= nb){                                                       \
    _Pragma("unroll")                                                        \
    for (int i=0; i<4; ++i)                                                  \
      _Pragma("unroll")                                                      \
      for (int gp=0; gp<4; ++gp){                                            \
        f32x2 e = { fexp2(L[gp][i][0]), fexp2(L[gp][i][1]) };                \
        accp[gp][i] += e;                                                    \
      }                                                                      \
  } else {                                                                   \
    float sel = ((m0_ + lr) < nb) ? 1.0f : 0.0f;                             \
    f32x2 selp = { sel, sel };                                               \
    _Pragma("unroll")                                                        \
    for (int i=0; i<4; ++i)                                                  \
      _Pragma("unroll")                                                      \
      for (int gp=0; gp<4; ++gp){                                            \
        f32x2 e = { fexp2(L[gp][i][0]), fexp2(L[gp][i][1]) };                \
        accp[gp][i] += selp * e;                                             \
      }                                                                      \
  }                                                                          \
} while(0)

__global__ __launch_bounds__(256) void attn_kernel(
    const unsigned short* __restrict__ qb, const unsigned short* __restrict__ kb,
    const float* __restrict__ Hw, const float* __restrict__ betas,
    const int* __restrict__ ds, float* __restrict__ partial)
{
  int tid = threadIdx.x;
  int l = tid & 63, w = tid >> 6;
  int bid = blockIdx.x;
  int nt4 = bid & 31, ms = (bid >> 5) & 7, b = bid >> 8;
  int nt = nt4*4 + w;
  int nb = ds[b];
  int n0 = nt*16;
  if (n0 >= nb) return;   // finalize never reads masked rows

  // w2p[h][gp] = betas[h]*log2e*Hw[h][2gp..2gp+1], wave-uniform (SGPRs)
  const float LOG2E = 1.4426950408889634f;
  f32x2 w2p[8][4];
  #pragma unroll
  for (int h=0; h<8; ++h){
    float bh = betas[h] * LOG2E;
    #pragma unroll
    for (int gp=0; gp<4; ++gp){
      float v0 = bh * Hw[h*8 + gp*2];
      float v1 = bh * Hw[h*8 + gp*2 + 1];
      w2p[h][gp][0] = __uint_as_float(__builtin_amdgcn_readfirstlane(__float_as_uint(v0)));
      w2p[h][gp][1] = __uint_as_float(__builtin_amdgcn_readfirstlane(__float_as_uint(v1)));
    }
  }

  int lr = l & 15, lk = (l >> 4)*8;
  // Q fragments: A-frag row = lane&15, k = (lane>>4)*8 + i (16B/lane loads)
  bf16x8 qf0[8], qf1[8];
  #pragma unroll
  for (int h=0; h<8; ++h){
    const unsigned short* qp = qb + (size_t)((b*8 + h)*2048 + n0 + lr)*64 + lk;
    qf0[h] = *(const bf16x8*)qp;
    qf1[h] = *(const bf16x8*)(qp + 32);
  }

  f32x2 accp[4][4];   // accp[gp][i] = (acc[2gp][i], acc[2gp+1][i])
  #pragma unroll
  for (int gp=0; gp<4; ++gp)
    #pragma unroll
    for (int i=0; i<4; ++i) accp[gp][i] = 0.0f;

  int mstart = ms*CHUNK;
  int mend = mstart + CHUNK; if (mend > nb) mend = nb;

  const unsigned short* kbase = kb + (size_t)(b*8)*2048*64 + (size_t)lr*64 + lk;

  if (mend > mstart){
    int tiles = (mend - mstart + 15) >> 4;   // 1..16, uniform per block
    bf16x8 kA0[8], kA1[8], kB0[8], kB1[8];
    LOADK(kA0, kA1, 0);
    int t = 0;
    for (; t + 2 <= tiles; t += 2){
      LOADK(kB0, kB1, t+1);
      COMPUTE(kA0, kA1, t);
      if (t + 2 < tiles) LOADK(kA0, kA1, t+2);
      COMPUTE(kB0, kB1, t+1);
    }
    if (t < tiles) COMPUTE(kA0, kA1, t);
  }

  // reduce over the 16 lanes sharing a row, write partials
  #pragma unroll
  for (int gp=0; gp<4; ++gp){
    #pragma unroll
    for (int c=0; c<2; ++c){
      int gg = gp*2 + c;
      #pragma unroll
      for (int i=0; i<4; ++i){
        float v = accp[gp][i][c];
        v += __shfl_xor(v, 1);
        v += __shfl_xor(v, 2);
        v += __shfl_xor(v, 4);
        v += __shfl_xor(v, 8);
        if (lr == gg){
          int n = n0 + (l>>4)*4 + i;
          partial[(size_t)((b*2048 + n)*8 + gg)*8 + ms] = v;
        }
      }
    }
  }
}

// ---------------------------------------------------------------------------
// Kernel 3: finalize. lse = log(sum of 8 split partials); skip rows >= nb;
// energy -= lse / beta_g.
// ---------------------------------------------------------------------------
__global__ __launch_bounds__(256) void fin_kernel(
    const float* __restrict__ partial, const float* __restrict__ betas,
    const int* __restrict__ ds, float* __restrict__ out)
{
  int tid = blockIdx.x*256 + threadIdx.x;       // 0..16383
  int g = tid & 7;
  float ibg = 1.0f / betas[g];
  float local = 0.0f;
  for (int idx = tid; idx < BB*NN*8; idx += 16384){
    int n = (idx >> 3) & 2047, b = idx >> 14;
    if (n < ds[b]){
      const float* p = partial + (size_t)idx*8;
      float ssum = 0.0f;
      #pragma unroll
      for (int s=0; s<8; ++s) ssum += p[s];
      local += __logf(ssum) * ibg;
    }
  }
  float v = local;
  #pragma unroll
  for (int m=1; m<64; m<<=1) v += __shfl_xor(v, m);
  if ((threadIdx.x & 63) == 0) atomicAdd(out, -v);
}

// ---------------------------------------------------------------------------
extern "C" void kernel_launch(void* const* d_in, const int* in_sizes, int n_in,
                              void* d_out, int out_size, void* d_ws, size_t ws_size,
                              hipStream_t stream)
{
  const float* g     = (const float*)d_in[0];
  const float* Wq    = (const float*)d_in[1];
  const float* Wk    = (const float*)d_in[2];
  const float* Hw    = (const float*)d_in[3];
  const float* betas = (const float*)d_in[4];
  const int*   ds    = (const int*)d_in[5];
  float* out = (float*)d_out;

  char* base = (char*)d_ws;
  unsigned short* gb      = (unsigned short*)(base);             //  4,194,304 B
  unsigned short* wb      = (unsigned short*)(base +  4194304);  //    524,288 B
  unsigned short* qb      = (unsigned short*)(base +  4718592);  //  8,388,608 B
  unsigned short* kb      = (unsigned short*)(base + 13107200);  //  8,388,608 B
  float*          partial = (float*)         (base + 21495808);  //  2,097,152 B

  cvt_kernel <<<dim3(2304), dim3(256), 0, stream>>>(g, Wq, Wk, gb, wb, out);
  proj_kernel<<<dim3(2048), dim3(256), 0, stream>>>(gb, wb, qb, kb);
  attn_kernel<<<dim3(1024), dim3(256), 0, stream>>>(qb, kb, Hw, betas, ds, partial);
  fin_kernel <<<dim3(64),   dim3(256), 0, stream>>>(partial, betas, ds, out);
}

// Round 5
// 83.050 us; speedup vs baseline: 1.7153x; 1.7153x over previous
//
#include <hip/hip_runtime.h>
#include <hip/hip_bf16.h>

// Problem constants
#define BB 4
#define NN 2048
#define DD 256
#define HH 8
#define ZZ 64
#define SPLIT 8
#define CHUNK (NN/SPLIT)   // 256

typedef __attribute__((ext_vector_type(8))) short bf16x8;
typedef __attribute__((ext_vector_type(4))) float f32x4;
typedef __attribute__((ext_vector_type(2))) float f32x2;
typedef __attribute__((ext_vector_type(4))) unsigned short us4;
typedef __attribute__((ext_vector_type(8))) unsigned short us8;

typedef __attribute__((address_space(3))) void  lds_void;
typedef __attribute__((address_space(1))) const void g_void;

static __device__ __forceinline__ unsigned short f2bf(float f){
  unsigned int u = __float_as_uint(f);
  u = (u + 0x7fffu + ((u>>16)&1u)) >> 16;   // RNE truncate to bf16
  return (unsigned short)u;
}

// raw v_exp_f32: computes 2^x (log2e folded into the mix weights)
static __device__ __forceinline__ float fexp2(float x){
  float r; asm("v_exp_f32 %0, %1" : "=v"(r) : "v"(x)); return r;
}

// ---------------------------------------------------------------------------
// Kernel 0: convert g (f32 -> bf16) and Wq||Wk (f32 -> bf16, [1024][256]),
// and zero the output scalar (d_out is poisoned before timing).
// ---------------------------------------------------------------------------
__global__ __launch_bounds__(256) void cvt_kernel(
    const float* __restrict__ g, const float* __restrict__ Wq,
    const float* __restrict__ Wk, unsigned short* __restrict__ gb,
    unsigned short* __restrict__ wb, float* __restrict__ out)
{
  int idx = blockIdx.x*256 + threadIdx.x;
  if (idx == 0) out[0] = 0.0f;
  if (idx < 524288){
    const float4 v = ((const float4*)g)[idx];
    us4 o = { f2bf(v.x), f2bf(v.y), f2bf(v.z), f2bf(v.w) };
    *(us4*)(gb + (size_t)idx*4) = o;
  } else {
    int j = idx - 524288;                   // 0..65535
    const float4 v = (j < 32768) ? ((const float4*)Wq)[j]
                                 : ((const float4*)Wk)[j - 32768];
    us4 o = { f2bf(v.x), f2bf(v.y), f2bf(v.z), f2bf(v.w) };
    int dst = (j < 32768) ? j*4 : 131072 + (j - 32768)*4;
    *(us4*)(wb + dst) = o;
  }
}

// ---------------------------------------------------------------------------
// Kernel 1: projection GEMM (unchanged — correct). q/k stored [b][h][n][z].
// ---------------------------------------------------------------------------
__global__ __launch_bounds__(256) void proj_kernel(
    const unsigned short* __restrict__ gb, const unsigned short* __restrict__ wb,
    unsigned short* __restrict__ qb, unsigned short* __restrict__ kb)
{
  __shared__ __align__(16) unsigned short As[64][40];
  __shared__ __align__(16) unsigned short Bs[64][40];
  int tid = threadIdx.x;
  int l = tid & 63, w = tid >> 6;
  int bid = blockIdx.x;
  int rt = bid >> 4, ct = bid & 15;
  int row0 = rt*64, col0 = ct*64;

  f32x4 acc[4];
  #pragma unroll
  for (int cf=0; cf<4; ++cf) acc[cf] = 0.0f;

  int sr = tid >> 2, sc = (tid & 3)*8;
  const unsigned short* ga = gb + (size_t)(row0 + sr)*256 + sc;
  const unsigned short* gw = wb + (size_t)(col0 + sr)*256 + sc;

  for (int ks=0; ks<8; ++ks){
    us8 av = *(const us8*)(ga + ks*32);
    us8 bv = *(const us8*)(gw + ks*32);
    *(us8*)&As[sr][sc] = av;
    *(us8*)&Bs[sr][sc] = bv;
    __syncthreads();
    bf16x8 af = *(const bf16x8*)&As[w*16 + (l&15)][(l>>4)*8];
    #pragma unroll
    for (int cf=0; cf<4; ++cf){
      bf16x8 bf = *(const bf16x8*)&Bs[cf*16 + (l&15)][(l>>4)*8];
      acc[cf] = __builtin_amdgcn_mfma_f32_16x16x32_bf16(af, bf, acc[cf], 0,0,0);
    }
    __syncthreads();
  }

  int h = (col0 >> 6) & 7;
  unsigned short* outp = (col0 < 512) ? qb : kb;
  #pragma unroll
  for (int cf=0; cf<4; ++cf){
    int z = cf*16 + (l & 15);
    #pragma unroll
    for (int i=0; i<4; ++i){
      int row = row0 + w*16 + (l>>4)*4 + i;
      int b_ = row >> 11, n_ = row & 2047;
      outp[(size_t)((b_*8 + h)*2048 + n_)*64 + z] = f2bf(acc[cf][i]);
    }
  }
}

// ---------------------------------------------------------------------------
// Kernel 2: fused scores + head-mix + exp accumulation, block-cooperative.
// Block = 4 waves x 16 q-rows = 64 rows; one 256-wide m-chunk per block.
// Per 16-m tile: K (8 heads x 16m x 64z = 16KB) staged into LDS by
// global_load_lds width=16 (coalesced 1KB/call, 4 calls/wave), double
// buffered; fragments read back as swizzled ds_read_b128 (c' = c ^ (r&7),
// inverse swizzle applied to the per-lane GLOBAL source per rule #21).
// One __syncthreads per tile (its vmcnt drain is the stage fence); stage of
// t+1 issued right after the barrier overlaps compute of t.
// Round-4 lesson: per-lane scattered 16B loads (16 cache lines per load)
// strangled the TA pipe; coalesced staging + LDS sharing cuts global traffic
// 4x and makes fragment reads LDS-cheap.
// ---------------------------------------------------------------------------

#define STAGE(BUF, m0_) do {                                                  \
  size_t moff_ = (size_t)(m0_)*64;                                            \
  __builtin_amdgcn_global_load_lds((g_void*)(kst0 + moff_),                   \
      (lds_void*)&lds[BUF][ldsw + 0],    16, 0, 0);                           \
  __builtin_amdgcn_global_load_lds((g_void*)(kst1 + moff_),                   \
      (lds_void*)&lds[BUF][ldsw + 1024], 16, 0, 0);                           \
  __builtin_amdgcn_global_load_lds((g_void*)(kst2 + moff_),                   \
      (lds_void*)&lds[BUF][ldsw + 2048], 16, 0, 0);                           \
  __builtin_amdgcn_global_load_lds((g_void*)(kst3 + moff_),                   \
      (lds_void*)&lds[BUF][ldsw + 3072], 16, 0, 0);                           \
} while(0)

#define COMPUTE(BUF, t) do {                                                  \
  int m0_ = mstart + (t)*16;                                                  \
  f32x2 L[4][4];                                                              \
  _Pragma("unroll")                                                           \
  for (int gp=0; gp<4; ++gp)                                                  \
    _Pragma("unroll")                                                         \
    for (int i=0; i<4; ++i) L[gp][i] = 0.0f;                                  \
  _Pragma("unroll")                                                           \
  for (int h=0; h<8; ++h){                                                    \
    bf16x8 k0 = *(const bf16x8*)&lds[BUF][h*2048 + soff0];                    \
    bf16x8 k1 = *(const bf16x8*)&lds[BUF][h*2048 + soff1];                    \
    f32x4 tt = 0.0f;                                                          \
    tt = __builtin_amdgcn_mfma_f32_16x16x32_bf16(qf0[h], k0, tt, 0,0,0);      \
    tt = __builtin_amdgcn_mfma_f32_16x16x32_bf16(qf1[h], k1, tt, 0,0,0);      \
    _Pragma("unroll")                                                         \
    for (int i=0; i<4; ++i){                                                  \
      f32x2 ss = { tt[i], tt[i] };                                            \
      _Pragma("unroll")                                                       \
      for (int gp=0; gp<4; ++gp)                                              \
        L[gp][i] = __builtin_elementwise_fma(w2p[h][gp], ss, L[gp][i]);       \
    }                                                                         \
  }                                                                           \
  if (m0_ + 16 <= nb){                                                        \
    _Pragma("unroll")                                                         \
    for (int i=0; i<4; ++i)                                                   \
      _Pragma("unroll")                                                       \
      for (int gp=0; gp<4; ++gp){                                             \
        f32x2 e = { fexp2(L[gp][i][0]), fexp2(L[gp][i][1]) };                 \
        accp[gp][i] += e;                                                     \
      }                                                                       \
  } else {                                                                    \
    float sel = ((m0_ + lr) < nb) ? 1.0f : 0.0f;                              \
    f32x2 selp = { sel, sel };                                                \
    _Pragma("unroll")                                                         \
    for (int i=0; i<4; ++i)                                                   \
      _Pragma("unroll")                                                       \
      for (int gp=0; gp<4; ++gp){                                             \
        f32x2 e = { fexp2(L[gp][i][0]), fexp2(L[gp][i][1]) };                 \
        accp[gp][i] += selp * e;                                              \
      }                                                                       \
  }                                                                           \
} while(0)

__global__ __launch_bounds__(256) void attn_kernel(
    const unsigned short* __restrict__ qb, const unsigned short* __restrict__ kb,
    const float* __restrict__ Hw, const float* __restrict__ betas,
    const int* __restrict__ ds, float* __restrict__ partial)
{
  __shared__ __align__(16) char lds[2][16384];

  int tid = threadIdx.x;
  int l = tid & 63, w = tid >> 6;
  int bid = blockIdx.x;
  // grid: bid = ((b*8 + ms)*32 + nblk)
  int nblk = bid & 31, ms = (bid >> 5) & 7, b = bid >> 8;
  int nb = ds[b];
  if (nblk*64 >= nb) return;            // block-uniform early exit
  int nt = nblk*4 + w;
  int n0 = nt*16;                        // may exceed nb: wave still staged

  // w2p[h][gp] = betas[h]*log2e*Hw[h][2gp..2gp+1], wave-uniform (SGPRs)
  const float LOG2E = 1.4426950408889634f;
  f32x2 w2p[8][4];
  #pragma unroll
  for (int h=0; h<8; ++h){
    float bh = betas[h] * LOG2E;
    #pragma unroll
    for (int gp=0; gp<4; ++gp){
      float v0 = bh * Hw[h*8 + gp*2];
      float v1 = bh * Hw[h*8 + gp*2 + 1];
      w2p[h][gp][0] = __uint_as_float(__builtin_amdgcn_readfirstlane(__float_as_uint(v0)));
      w2p[h][gp][1] = __uint_as_float(__builtin_amdgcn_readfirstlane(__float_as_uint(v1)));
    }
  }

  int lr = l & 15, lk = (l >> 4)*8;
  // Q fragments (once per block; scatter cost amortized over the m-sweep)
  bf16x8 qf0[8], qf1[8];
  #pragma unroll
  for (int h=0; h<8; ++h){
    const unsigned short* qp = qb + (size_t)((b*8 + h)*2048 + n0 + lr)*64 + lk;
    qf0[h] = *(const bf16x8*)qp;
    qf1[h] = *(const bf16x8*)(qp + 32);
  }

  f32x2 accp[4][4];   // accp[gp][i] = (acc[2gp][i], acc[2gp+1][i])
  #pragma unroll
  for (int gp=0; gp<4; ++gp)
    #pragma unroll
    for (int i=0; i<4; ++i) accp[gp][i] = 0.0f;

  int mstart = ms*CHUNK;
  int mend = mstart + CHUNK; if (mend > nb) mend = nb;
  int tiles = (mend > mstart) ? ((mend - mstart + 15) >> 4) : 0;

  // --- staging setup: wave w stages heads 2w, 2w+1 (4 x 1KB calls/tile) ---
  // LDS 16B-unit (r, c') of a head-tile holds global (row r, col c'^(r&7)).
  int rl = l >> 3;            // 0..7  (row within 8-row half)
  int cl = l & 7;             // 0..7  (swizzled 16B column c')
  int gcol = ((cl ^ rl) * 8); // inverse-swizzled global column (elements)
  int ldsw = w * 4096;        // this wave's head pair in each buffer
  const unsigned short* kst0 = kb + ((size_t)((b*8 + 2*w    )*2048) +     rl)*64 + gcol;
  const unsigned short* kst1 = kb + ((size_t)((b*8 + 2*w    )*2048) + 8 + rl)*64 + gcol;
  const unsigned short* kst2 = kb + ((size_t)((b*8 + 2*w + 1)*2048) +     rl)*64 + gcol;
  const unsigned short* kst3 = kb + ((size_t)((b*8 + 2*w + 1)*2048) + 8 + rl)*64 + gcol;

  // swizzled fragment read offsets (within a head-tile)
  int soff0 = lr*128 + (((l>>4)    ^ (lr & 7))*16);
  int soff1 = lr*128 + ((((l>>4)+4) ^ (lr & 7))*16);

  if (tiles > 0){
    STAGE(0, mstart);
    int t = 0;
    for (; t + 2 <= tiles; t += 2){
      __syncthreads();                       // drains stage(t) + prior reads
      STAGE(1, mstart + (t+1)*16);           // overlaps compute(t)
      COMPUTE(0, t);
      __syncthreads();                       // drains stage(t+1) + reads
      if (t + 2 < tiles) STAGE(0, mstart + (t+2)*16);
      COMPUTE(1, t+1);
    }
    if (t < tiles){                          // odd tail
      __syncthreads();
      COMPUTE(0, t);
    }
  }

  // reduce over the 16 lanes sharing a row, write partials
  #pragma unroll
  for (int gp=0; gp<4; ++gp){
    #pragma unroll
    for (int c=0; c<2; ++c){
      int gg = gp*2 + c;
      #pragma unroll
      for (int i=0; i<4; ++i){
        float v = accp[gp][i][c];
        v += __shfl_xor(v, 1);
        v += __shfl_xor(v, 2);
        v += __shfl_xor(v, 4);
        v += __shfl_xor(v, 8);
        if (lr == gg){
          int n = n0 + (l>>4)*4 + i;
          partial[(size_t)((b*2048 + n)*8 + gg)*8 + ms] = v;
        }
      }
    }
  }
}

// ---------------------------------------------------------------------------
// Kernel 3: finalize. lse = log(sum of 8 split partials); skip rows >= nb;
// energy -= lse / beta_g.
// ---------------------------------------------------------------------------
__global__ __launch_bounds__(256) void fin_kernel(
    const float* __restrict__ partial, const float* __restrict__ betas,
    const int* __restrict__ ds, float* __restrict__ out)
{
  int tid = blockIdx.x*256 + threadIdx.x;       // 0..16383
  int g = tid & 7;
  float ibg = 1.0f / betas[g];
  float local = 0.0f;
  for (int idx = tid; idx < BB*NN*8; idx += 16384){
    int n = (idx >> 3) & 2047, b = idx >> 14;
    if (n < ds[b]){
      const float* p = partial + (size_t)idx*8;
      float ssum = 0.0f;
      #pragma unroll
      for (int s=0; s<8; ++s) ssum += p[s];
      local += __logf(ssum) * ibg;
    }
  }
  float v = local;
  #pragma unroll
  for (int m=1; m<64; m<<=1) v += __shfl_xor(v, m);
  if ((threadIdx.x & 63) == 0) atomicAdd(out, -v);
}

// ---------------------------------------------------------------------------
extern "C" void kernel_launch(void* const* d_in, const int* in_sizes, int n_in,
                              void* d_out, int out_size, void* d_ws, size_t ws_size,
                              hipStream_t stream)
{
  const float* g     = (const float*)d_in[0];
  const float* Wq    = (const float*)d_in[1];
  const float* Wk    = (const float*)d_in[2];
  const float* Hw    = (const float*)d_in[3];
  const float* betas = (const float*)d_in[4];
  const int*   ds    = (const int*)d_in[5];
  float* out = (float*)d_out;

  char* base = (char*)d_ws;
  unsigned short* gb      = (unsigned short*)(base);             //  4,194,304 B
  unsigned short* wb      = (unsigned short*)(base +  4194304);  //    524,288 B
  unsigned short* qb      = (unsigned short*)(base +  4718592);  //  8,388,608 B
  unsigned short* kb      = (unsigned short*)(base + 13107200);  //  8,388,608 B
  float*          partial = (float*)         (base + 21495808);  //  2,097,152 B

  cvt_kernel <<<dim3(2304), dim3(256), 0, stream>>>(g, Wq, Wk, gb, wb, out);
  proj_kernel<<<dim3(2048), dim3(256), 0, stream>>>(gb, wb, qb, kb);
  attn_kernel<<<dim3(1024), dim3(256), 0, stream>>>(qb, kb, Hw, betas, ds, partial);
  fin_kernel <<<dim3(64),   dim3(256), 0, stream>>>(partial, betas, ds, out);
}